// Round 1
// baseline (45566.299 us; speedup 1.0000x reference)
//
#include <hip/hip_runtime.h>
#include <hip/hip_bf16.h>
#include <math.h>

namespace {

constexpr int B = 256, S = 64, H = 768, L = 12, NH = 12, F = 3072, T = 11;
constexpr int BS = B * S;            // 16384 rows
constexpr int RC = 4096;             // rows per chunk
constexpr int NC = BS / RC;          // 4 chunks

__device__ __forceinline__ float gelu_tanh(float v) {
  return 0.5f * v * (1.0f + tanhf(0.7978845608028654f * (v + 0.044715f * v * v * v)));
}

// C[M,N] = A[M,K] @ W[K,N] + bias ; ACT==1 -> tanh-GELU
template <int ACT>
__global__ __launch_bounds__(256) void gemm_kernel(const float* __restrict__ A,
                                                   const float* __restrict__ W,
                                                   const float* __restrict__ bias,
                                                   float* __restrict__ C,
                                                   int M, int N, int K) {
  __shared__ float As[16][65];   // As[k][m]
  __shared__ float Bs[16][68];   // Bs[k][n] (pad 68 keeps float4-aligned cols, 2-way banks)
  const int tid = threadIdx.x;
  const int bm = blockIdx.y * 64;
  const int bn = blockIdx.x * 64;
  const int tx = tid & 15, ty = tid >> 4;
  const int ar = tid >> 2, ak = (tid & 3) << 2;
  const int br = tid >> 4, bc = (tid & 15) << 2;
  float acc[4][4] = {};
  for (int k0 = 0; k0 < K; k0 += 16) {
    float4 av = *(const float4*)(A + (size_t)(bm + ar) * K + (k0 + ak));
    As[ak + 0][ar] = av.x;
    As[ak + 1][ar] = av.y;
    As[ak + 2][ar] = av.z;
    As[ak + 3][ar] = av.w;
    float4 bv = *(const float4*)(W + (size_t)(k0 + br) * N + (bn + bc));
    Bs[br][bc + 0] = bv.x;
    Bs[br][bc + 1] = bv.y;
    Bs[br][bc + 2] = bv.z;
    Bs[br][bc + 3] = bv.w;
    __syncthreads();
#pragma unroll
    for (int k = 0; k < 16; ++k) {
      float a[4], bb[4];
#pragma unroll
      for (int i = 0; i < 4; ++i) a[i] = As[k][ty * 4 + i];
#pragma unroll
      for (int j = 0; j < 4; ++j) bb[j] = Bs[k][tx * 4 + j];
#pragma unroll
      for (int i = 0; i < 4; ++i)
#pragma unroll
        for (int j = 0; j < 4; ++j) acc[i][j] += a[i] * bb[j];
    }
    __syncthreads();
  }
#pragma unroll
  for (int i = 0; i < 4; ++i) {
    int m = bm + ty * 4 + i;
#pragma unroll
    for (int j = 0; j < 4; ++j) {
      int n = bn + tx * 4 + j;
      float v = acc[i][j] + bias[n];
      if (ACT == 1) v = gelu_tanh(v);
      C[(size_t)m * N + n] = v;
    }
  }
}

// One block per (local batch, head): scores -> softmax -> P@V, all in LDS.
__global__ __launch_bounds__(256) void attn_kernel(const float* __restrict__ qkv,
                                                   const int* __restrict__ mask,
                                                   float* __restrict__ outp, int b0) {
  __shared__ float smem[64 * 64 + 64 * 66 + 64 * 64];  // Qs | KsT | Vs ; Ps aliases Qs/KsT
  float (*Qs)[64] = (float (*)[64])smem;
  float (*KsT)[66] = (float (*)[66])(smem + 64 * 64);
  float (*Vs)[64] = (float (*)[64])(smem + 64 * 64 + 64 * 66);
  float (*Ps)[65] = (float (*)[65])smem;

  const int bl = blockIdx.x / NH;
  const int h = blockIdx.x % NH;
  const int bg = b0 + bl;
  const int tid = threadIdx.x;
  const int lane = tid & 63;
  const int w = tid >> 6;

  for (int i = 0; i < 16; ++i) {
    int idx = tid + i * 256;
    int r = idx >> 6, d = idx & 63;
    size_t base = (size_t)(bl * 64 + r) * (3 * H) + h * 64 + d;
    Qs[r][d] = qkv[base];
    KsT[d][r] = qkv[base + H];
    Vs[r][d] = qkv[base + 2 * H];
  }
  __syncthreads();

  float sc[16];
#pragma unroll
  for (int i = 0; i < 16; ++i) sc[i] = 0.f;
  for (int d = 0; d < 64; ++d) {
    float kv = KsT[d][lane];
#pragma unroll
    for (int i = 0; i < 16; ++i) sc[i] += Qs[w + 4 * i][d] * kv;  // Qs read is broadcast
  }
  __syncthreads();  // all Qs/KsT reads done; Ps may alias them now
  float biask = (1.0f - (float)mask[bg * S + lane]) * -1e9f;
#pragma unroll
  for (int i = 0; i < 16; ++i) Ps[w + 4 * i][lane] = sc[i] * 0.125f + biask;
  __syncthreads();

  if (tid < 64) {  // one row per lane, pad-65 keeps this 2-way
    int q = tid;
    float mx = -1e30f;
    for (int k = 0; k < 64; ++k) mx = fmaxf(mx, Ps[q][k]);
    float sum = 0.f;
    for (int k = 0; k < 64; ++k) {
      float e = expf(Ps[q][k] - mx);
      Ps[q][k] = e;
      sum += e;
    }
    float inv = 1.0f / sum;
    for (int k = 0; k < 64; ++k) Ps[q][k] *= inv;
  }
  __syncthreads();

  float o[16];
#pragma unroll
  for (int i = 0; i < 16; ++i) o[i] = 0.f;
  for (int k = 0; k < 64; ++k) {
    float vv = Vs[k][lane];
#pragma unroll
    for (int i = 0; i < 16; ++i) o[i] += Ps[w + 4 * i][k] * vv;  // Ps read is broadcast
  }
#pragma unroll
  for (int i = 0; i < 16; ++i) {
    int q = w + 4 * i;
    outp[(size_t)(bl * 64 + q) * H + h * 64 + lane] = o[i];
  }
}

__global__ __launch_bounds__(256) void embed_ln_kernel(const int* __restrict__ ids,
                                                       const float* __restrict__ we,
                                                       const float* __restrict__ pe,
                                                       const float* __restrict__ te,
                                                       const float* __restrict__ g,
                                                       const float* __restrict__ bta,
                                                       float* __restrict__ x) {
  __shared__ float buf[H];
  __shared__ float red[256];
  const int row = blockIdx.x;
  const int s = row % S;
  const int tid = threadIdx.x;
  const int id = ids[row];
  float local = 0.f;
  for (int i = tid; i < H; i += 256) {
    float v = we[(size_t)id * H + i] + pe[(size_t)s * H + i] + te[i];
    buf[i] = v;
    local += v;
  }
  red[tid] = local;
  __syncthreads();
  for (int st = 128; st > 0; st >>= 1) {
    if (tid < st) red[tid] += red[tid + st];
    __syncthreads();
  }
  float mean = red[0] * (1.0f / H);
  __syncthreads();
  float ls = 0.f;
  for (int i = tid; i < H; i += 256) {
    float d = buf[i] - mean;
    ls += d * d;
  }
  red[tid] = ls;
  __syncthreads();
  for (int st = 128; st > 0; st >>= 1) {
    if (tid < st) red[tid] += red[tid + st];
    __syncthreads();
  }
  float inv = 1.0f / sqrtf(red[0] * (1.0f / H) + 1e-12f);
  for (int i = tid; i < H; i += 256) {
    x[(size_t)row * H + i] = (buf[i] - mean) * inv * g[i] + bta[i];
  }
}

// x = LayerNorm(x + y) * g + b   (y already includes the GEMM bias)
__global__ __launch_bounds__(256) void add_ln_kernel(float* __restrict__ x,
                                                     const float* __restrict__ y,
                                                     const float* __restrict__ g,
                                                     const float* __restrict__ bta) {
  __shared__ float buf[H];
  __shared__ float red[256];
  const size_t row = blockIdx.x;
  const int tid = threadIdx.x;
  float local = 0.f;
  for (int i = tid; i < H; i += 256) {
    float v = x[row * H + i] + y[row * H + i];
    buf[i] = v;
    local += v;
  }
  red[tid] = local;
  __syncthreads();
  for (int st = 128; st > 0; st >>= 1) {
    if (tid < st) red[tid] += red[tid + st];
    __syncthreads();
  }
  float mean = red[0] * (1.0f / H);
  __syncthreads();
  float ls = 0.f;
  for (int i = tid; i < H; i += 256) {
    float d = buf[i] - mean;
    ls += d * d;
  }
  red[tid] = ls;
  __syncthreads();
  for (int st = 128; st > 0; st >>= 1) {
    if (tid < st) red[tid] += red[tid + st];
    __syncthreads();
  }
  float inv = 1.0f / sqrtf(red[0] * (1.0f / H) + 1e-12f);
  for (int i = tid; i < H; i += 256) {
    x[row * H + i] = (buf[i] - mean) * inv * g[i] + bta[i];
  }
}

__global__ __launch_bounds__(256) void fc_kernel(const float* __restrict__ x,
                                                 const float* __restrict__ w,
                                                 const float* __restrict__ bias,
                                                 float* __restrict__ logits) {
  __shared__ float xs[H];
  const size_t row = blockIdx.x;
  const int tid = threadIdx.x;
  for (int i = tid; i < H; i += 256) xs[i] = x[row * H + i];
  __syncthreads();
  const int j = tid >> 4, l = tid & 15;
  if (j < T) {
    float s = 0.f;
    for (int k = l; k < H; k += 16) s += xs[k] * w[(size_t)k * T + j];
#pragma unroll
    for (int d = 8; d > 0; d >>= 1) s += __shfl_down(s, d, 16);
    if (l == 0) logits[row * T + j] = s + bias[j];
  }
}

__global__ __launch_bounds__(64) void crf_llh_kernel(const float* __restrict__ em,
                                                     const int* __restrict__ label,
                                                     const int* __restrict__ mask,
                                                     const float* __restrict__ start,
                                                     const float* __restrict__ endw,
                                                     const float* __restrict__ trans,
                                                     float* __restrict__ llh) {
  const int b = blockIdx.x;
  const int c = threadIdx.x;
  __shared__ float alpha[T];
  __shared__ float tr[T][T];
  for (int i = c; i < T * T; i += 64) tr[i / T][i % T] = trans[i];
  if (c < T) alpha[c] = start[c] + em[(size_t)b * S * T + c];
  __syncthreads();
  for (int s = 1; s < S; ++s) {
    float a = 0.f;
    if (c < T) {
      float mx = -1e30f;
      for (int p = 0; p < T; ++p) mx = fmaxf(mx, alpha[p] + tr[p][c]);
      float sum = 0.f;
      for (int p = 0; p < T; ++p) sum += expf(alpha[p] + tr[p][c] - mx);
      a = mx + logf(sum) + em[((size_t)b * S + s) * T + c];
    }
    __syncthreads();
    if (c < T) {
      float m = (float)mask[b * S + s];
      alpha[c] = (m > 0.f) ? a : alpha[c];
    }
    __syncthreads();
  }
  if (c == 0) {
    float mx = -1e30f;
    for (int p = 0; p < T; ++p) mx = fmaxf(mx, alpha[p] + endw[p]);
    float sum = 0.f;
    for (int p = 0; p < T; ++p) sum += expf(alpha[p] + endw[p] - mx);
    float denom = mx + logf(sum);

    int t0 = label[b * S];
    float score = start[t0] + em[(size_t)b * S * T + t0];
    int prev = t0;
    for (int s = 1; s < S; ++s) {
      int tc = label[b * S + s];
      float m = (float)mask[b * S + s];
      score += (tr[prev][tc] + em[((size_t)b * S + s) * T + tc]) * m;
      prev = tc;
    }
    int msum = 0;
    for (int s = 0; s < S; ++s) msum += mask[b * S + s];
    score += endw[label[b * S + (msum - 1)]];
    llh[b] = score - denom;
  }
}

__global__ __launch_bounds__(256) void loss_kernel(const float* __restrict__ llh,
                                                   float* __restrict__ out) {
  __shared__ float red[256];
  const int tid = threadIdx.x;
  red[tid] = llh[tid];  // B == 256
  __syncthreads();
  for (int st = 128; st > 0; st >>= 1) {
    if (tid < st) red[tid] += red[tid + st];
    __syncthreads();
  }
  if (tid == 0) out[BS] = -red[0] * (1.0f / B);
}

__global__ __launch_bounds__(64) void viterbi_kernel(const float* __restrict__ em,
                                                     const int* __restrict__ mask,
                                                     const float* __restrict__ start,
                                                     const float* __restrict__ endw,
                                                     const float* __restrict__ trans,
                                                     float* __restrict__ pred) {
  const int b = blockIdx.x;
  const int c = threadIdx.x;
  __shared__ float sc[T];
  __shared__ float tr[T][T];
  __shared__ int hist[S - 1][T];
  for (int i = c; i < T * T; i += 64) tr[i / T][i % T] = trans[i];
  if (c < T) sc[c] = start[c] + em[(size_t)b * S * T + c];
  __syncthreads();
  for (int s = 1; s < S; ++s) {
    float bestv = -1e30f;
    int bestp = 0;
    if (c < T) {
      for (int p = 0; p < T; ++p) {
        float v = sc[p] + tr[p][c];
        if (v > bestv) { bestv = v; bestp = p; }  // strict > == first-occurrence argmax
      }
      hist[s - 1][c] = bestp;
    }
    __syncthreads();
    if (c < T) {
      float m = (float)mask[b * S + s];
      sc[c] = (m > 0.f) ? (bestv + em[((size_t)b * S + s) * T + c]) : sc[c];
    }
    __syncthreads();
  }
  if (c == 0) {
    float bv = -1e30f;
    int last = 0;
    for (int p = 0; p < T; ++p) {
      float v = sc[p] + endw[p];
      if (v > bv) { bv = v; last = p; }
    }
    pred[b * S + (S - 1)] = (float)last;
    int t = last;
    for (int hs = S - 2; hs >= 0; --hs) {
      if (mask[b * S + hs + 1] > 0) t = hist[hs][t];
      pred[b * S + hs] = (float)t;
    }
  }
}

}  // namespace

extern "C" void kernel_launch(void* const* d_in, const int* in_sizes, int n_in,
                              void* d_out, int out_size, void* d_ws, size_t ws_size,
                              hipStream_t stream) {
  (void)in_sizes; (void)n_in; (void)out_size; (void)ws_size;
  const int* input_ids = (const int*)d_in[0];
  const int* attn_mask = (const int*)d_in[1];
  const int* label = (const int*)d_in[2];
  const float* word_emb = (const float*)d_in[3];
  const float* pos_emb = (const float*)d_in[4];
  const float* tok_emb = (const float*)d_in[5];
  const float* eg = (const float*)d_in[6];
  const float* ebt = (const float*)d_in[7];
  const float* Wqkv = (const float*)d_in[8];
  const float* bqkv = (const float*)d_in[9];
  const float* Wo = (const float*)d_in[10];
  const float* bo = (const float*)d_in[11];
  const float* ln1g = (const float*)d_in[12];
  const float* ln1b = (const float*)d_in[13];
  const float* W1 = (const float*)d_in[14];
  const float* b1 = (const float*)d_in[15];
  const float* W2 = (const float*)d_in[16];
  const float* b2 = (const float*)d_in[17];
  const float* ln2g = (const float*)d_in[18];
  const float* ln2b = (const float*)d_in[19];
  const float* fc_w = (const float*)d_in[20];
  const float* fc_b = (const float*)d_in[21];
  const float* crf_start = (const float*)d_in[22];
  const float* crf_end = (const float*)d_in[23];
  const float* crf_trans = (const float*)d_in[24];
  float* out = (float*)d_out;

  float* ws = (float*)d_ws;
  const size_t XE = (size_t)BS * H;
  float* x = ws;                       // [BS,H] residual stream
  float* tmpA = x + XE;                // [BS,H] gemm outputs pre-LN
  float* big = tmpA + XE;              // [RC,F] chunk scratch (qkv | attn-out, or ffn-h)
  float* logits = big + (size_t)RC * F; // [BS,T]
  float* llh = logits + (size_t)BS * T; // [B]

  float* qkvC = big;                    // [RC, 3H]
  float* attnC = big + (size_t)RC * 3 * H;  // [RC, H]

  embed_ln_kernel<<<BS, 256, 0, stream>>>(input_ids, word_emb, pos_emb, tok_emb, eg, ebt, x);

  for (int l = 0; l < L; ++l) {
    const float* wqkv_l = Wqkv + (size_t)l * H * 3 * H;
    const float* bqkv_l = bqkv + (size_t)l * 3 * H;
    const float* wo_l = Wo + (size_t)l * H * H;
    const float* bo_l = bo + (size_t)l * H;
    const float* g1 = ln1g + (size_t)l * H;
    const float* be1 = ln1b + (size_t)l * H;
    const float* w1_l = W1 + (size_t)l * H * F;
    const float* b1_l = b1 + (size_t)l * F;
    const float* w2_l = W2 + (size_t)l * F * H;
    const float* b2_l = b2 + (size_t)l * H;
    const float* g2 = ln2g + (size_t)l * H;
    const float* be2 = ln2b + (size_t)l * H;

    for (int ch = 0; ch < NC; ++ch) {
      const float* xo = x + (size_t)ch * RC * H;
      gemm_kernel<0><<<dim3(3 * H / 64, RC / 64), 256, 0, stream>>>(
          xo, wqkv_l, bqkv_l, qkvC, RC, 3 * H, H);
      attn_kernel<<<(RC / S) * NH, 256, 0, stream>>>(qkvC, attn_mask, attnC, ch * (RC / S));
      gemm_kernel<0><<<dim3(H / 64, RC / 64), 256, 0, stream>>>(
          attnC, wo_l, bo_l, tmpA + (size_t)ch * RC * H, RC, H, H);
    }
    add_ln_kernel<<<BS, 256, 0, stream>>>(x, tmpA, g1, be1);

    for (int ch = 0; ch < NC; ++ch) {
      const float* xo = x + (size_t)ch * RC * H;
      gemm_kernel<1><<<dim3(F / 64, RC / 64), 256, 0, stream>>>(
          xo, w1_l, b1_l, big, RC, F, H);
      gemm_kernel<0><<<dim3(H / 64, RC / 64), 256, 0, stream>>>(
          big, w2_l, b2_l, tmpA + (size_t)ch * RC * H, RC, H, F);
    }
    add_ln_kernel<<<BS, 256, 0, stream>>>(x, tmpA, g2, be2);
  }

  fc_kernel<<<BS, 256, 0, stream>>>(x, fc_w, fc_b, logits);
  crf_llh_kernel<<<B, 64, 0, stream>>>(logits, label, attn_mask, crf_start, crf_end, crf_trans, llh);
  loss_kernel<<<1, 256, 0, stream>>>(llh, out);
  viterbi_kernel<<<B, 64, 0, stream>>>(logits, attn_mask, crf_start, crf_end, crf_trans, out);
}

// Round 2
// 14955.453 us; speedup vs baseline: 3.0468x; 3.0468x over previous
//
#include <hip/hip_runtime.h>
#include <hip/hip_bf16.h>
#include <math.h>

namespace {

constexpr int B = 256, S = 64, H = 768, L = 12, NH = 12, F = 3072, T = 11;
constexpr int BS = B * S;   // 16384 rows
constexpr int RC = 4096;    // rows per chunk (QKV/attn phase)
constexpr int NC = BS / RC;
constexpr int RF = 8192;    // rows per chunk (FFN phase)
constexpr int NF = BS / RF;

typedef __attribute__((ext_vector_type(8))) short short8;
typedef __attribute__((ext_vector_type(4))) float f32x4;

__device__ __forceinline__ float gelu_tanh(float v) {
  return 0.5f * v * (1.0f + tanhf(0.7978845608028654f * (v + 0.044715f * v * v * v)));
}

// RNE float->bf16 (bit-exact, header-independent)
__device__ __forceinline__ ushort f2bf(float v) {
  union { float f; unsigned u; } c; c.f = v;
  unsigned r = (c.u + 0x7fffu + ((c.u >> 16) & 1u)) >> 16;
  return (ushort)r;
}
__device__ __forceinline__ float bf2f(ushort u) {
  union { unsigned u; float f; } c; c.u = ((unsigned)u) << 16;
  return c.f;
}
__device__ __forceinline__ void split2(float v, ushort& hi, ushort& lo) {
  hi = f2bf(v);
  lo = f2bf(v - bf2f(hi));
}

#define GLOAD_LDS16(gptr, ldsptr)                                                        \
  __builtin_amdgcn_global_load_lds((const __attribute__((address_space(1))) void*)(gptr), \
                                   (__attribute__((address_space(3))) void*)(ldsptr), 16, 0, 0)

// C[M,N] = (Ahi+Alo)[M,K] @ (Bhi+Blo)[N,K]^T + bias, fp32 accum via 3 bf16 MFMA products.
// ACT==0: write Cf fp32. ACT==1: write gelu(v) split into Chi/Clo bf16.
template <int ACT>
__global__ __launch_bounds__(256) void gemm_mfma(const ushort* __restrict__ Ahi,
                                                 const ushort* __restrict__ Alo,
                                                 const ushort* __restrict__ Bhi,
                                                 const ushort* __restrict__ Blo,
                                                 const float* __restrict__ bias,
                                                 float* __restrict__ Cf,
                                                 ushort* __restrict__ Chi,
                                                 ushort* __restrict__ Clo,
                                                 int M, int N, int K) {
  __shared__ ushort sA[2 * 128 * 32];  // [hi|lo][m 0..127][kk 0..31]
  __shared__ ushort sB[2 * 128 * 32];  // [hi|lo][n 0..127][kk 0..31]
  const int tid = threadIdx.x;
  const int w = tid >> 6;
  const int lane = tid & 63;
  const int bm = blockIdx.y * 128;
  const int bn = blockIdx.x * 128;
  // staging: row within 16-row group = lane/4, 8-elem k block = lane%4
  const int sr = lane >> 2;
  const int sc = (lane & 3) << 3;
  const int r0 = w * 32 + sr;
  const int r1 = r0 + 16;
  // fragment read indices (16x16x32 bf16: row = lane%16, k = 8*(lane/16)+0..7)
  const int wm = w >> 1, wn = w & 1;
  const int fr = lane & 15;
  const int fk = (lane >> 4) << 3;

  f32x4 acc[4][4] = {};

  for (int k0 = 0; k0 < K; k0 += 32) {
    const size_t a0 = (size_t)(bm + r0) * K + k0 + sc;
    const size_t a1 = (size_t)(bm + r1) * K + k0 + sc;
    const size_t b0 = (size_t)(bn + r0) * K + k0 + sc;
    const size_t b1 = (size_t)(bn + r1) * K + k0 + sc;
    GLOAD_LDS16(Ahi + a0, sA + (w * 32) * 32);
    GLOAD_LDS16(Ahi + a1, sA + (w * 32 + 16) * 32);
    GLOAD_LDS16(Alo + a0, sA + (128 + w * 32) * 32);
    GLOAD_LDS16(Alo + a1, sA + (128 + w * 32 + 16) * 32);
    GLOAD_LDS16(Bhi + b0, sB + (w * 32) * 32);
    GLOAD_LDS16(Bhi + b1, sB + (w * 32 + 16) * 32);
    GLOAD_LDS16(Blo + b0, sB + (128 + w * 32) * 32);
    GLOAD_LDS16(Blo + b1, sB + (128 + w * 32 + 16) * 32);
    __syncthreads();  // drains vmcnt -> LDS tiles ready

    short8 ah[4], al[4], bh[4], bl[4];
#pragma unroll
    for (int i = 0; i < 4; ++i) {
      ah[i] = *(const short8*)(sA + (wm * 64 + i * 16 + fr) * 32 + fk);
      al[i] = *(const short8*)(sA + (128 + wm * 64 + i * 16 + fr) * 32 + fk);
      bh[i] = *(const short8*)(sB + (wn * 64 + i * 16 + fr) * 32 + fk);
      bl[i] = *(const short8*)(sB + (128 + wn * 64 + i * 16 + fr) * 32 + fk);
    }
#pragma unroll
    for (int mi = 0; mi < 4; ++mi)
#pragma unroll
      for (int ni = 0; ni < 4; ++ni) {
        acc[mi][ni] = __builtin_amdgcn_mfma_f32_16x16x32_bf16(ah[mi], bh[ni], acc[mi][ni], 0, 0, 0);
        acc[mi][ni] = __builtin_amdgcn_mfma_f32_16x16x32_bf16(ah[mi], bl[ni], acc[mi][ni], 0, 0, 0);
        acc[mi][ni] = __builtin_amdgcn_mfma_f32_16x16x32_bf16(al[mi], bh[ni], acc[mi][ni], 0, 0, 0);
      }
    __syncthreads();  // all reads done before next-tile overwrite
  }

  const int erow = (lane >> 4) << 2;  // C/D: col=lane&15, row=(lane>>4)*4+e (m89-verified)
#pragma unroll
  for (int ni = 0; ni < 4; ++ni) {
    const int col = bn + wn * 64 + ni * 16 + fr;
    const float bv = bias[col];
#pragma unroll
    for (int mi = 0; mi < 4; ++mi) {
#pragma unroll
      for (int e = 0; e < 4; ++e) {
        const int row = bm + wm * 64 + mi * 16 + erow + e;
        float v = acc[mi][ni][e] + bv;
        if (ACT == 1) {
          v = gelu_tanh(v);
          ushort hi, lo;
          split2(v, hi, lo);
          Chi[(size_t)row * N + col] = hi;
          Clo[(size_t)row * N + col] = lo;
        } else {
          Cf[(size_t)row * N + col] = v;
        }
      }
    }
  }
}

// W[K][N] fp32 -> WhiT/WloT[N][K] bf16 (transpose + hi/lo split), 32x32 LDS tiles.
__global__ __launch_bounds__(256) void convert_w_t(const float* __restrict__ W,
                                                   ushort* __restrict__ WhiT,
                                                   ushort* __restrict__ WloT, int K, int N) {
  __shared__ float tile[32][33];
  const int kb = blockIdx.y * 32, nb = blockIdx.x * 32;
  const int tr = threadIdx.x >> 5;  // 0..7
  const int tc = threadIdx.x & 31;
#pragma unroll
  for (int p = 0; p < 4; ++p) {
    int r = tr + p * 8;
    tile[r][tc] = W[(size_t)(kb + r) * N + nb + tc];
  }
  __syncthreads();
#pragma unroll
  for (int p = 0; p < 4; ++p) {
    int n = tr + p * 8;
    float v = tile[tc][n];
    ushort hi, lo;
    split2(v, hi, lo);
    size_t o = (size_t)(nb + n) * K + kb + tc;
    WhiT[o] = hi;
    WloT[o] = lo;
  }
}

// One block per (local batch, head): scores -> softmax -> P@V in LDS; out = hi/lo bf16.
__global__ __launch_bounds__(256) void attn_kernel(const float* __restrict__ qkv,
                                                   const int* __restrict__ mask,
                                                   ushort* __restrict__ outHi,
                                                   ushort* __restrict__ outLo, int b0) {
  __shared__ float smem[64 * 64 + 64 * 66 + 64 * 64];  // Qs | KsT | Vs ; Ps aliases Qs/KsT
  float (*Qs)[64] = (float (*)[64])smem;
  float (*KsT)[66] = (float (*)[66])(smem + 64 * 64);
  float (*Vs)[64] = (float (*)[64])(smem + 64 * 64 + 64 * 66);
  float (*Ps)[65] = (float (*)[65])smem;

  const int bl = blockIdx.x / NH;
  const int hh = blockIdx.x % NH;
  const int bg = b0 + bl;
  const int tid = threadIdx.x;
  const int lane = tid & 63;
  const int w = tid >> 6;

  for (int i = 0; i < 16; ++i) {
    int idx = tid + i * 256;
    int r = idx >> 6, d = idx & 63;
    size_t base = (size_t)(bl * 64 + r) * (3 * H) + hh * 64 + d;
    Qs[r][d] = qkv[base];
    KsT[d][r] = qkv[base + H];
    Vs[r][d] = qkv[base + 2 * H];
  }
  __syncthreads();

  float sc[16];
#pragma unroll
  for (int i = 0; i < 16; ++i) sc[i] = 0.f;
  for (int d = 0; d < 64; ++d) {
    float kv = KsT[d][lane];
#pragma unroll
    for (int i = 0; i < 16; ++i) sc[i] += Qs[w + 4 * i][d] * kv;
  }
  __syncthreads();
  float biask = (1.0f - (float)mask[bg * S + lane]) * -1e9f;
#pragma unroll
  for (int i = 0; i < 16; ++i) Ps[w + 4 * i][lane] = sc[i] * 0.125f + biask;
  __syncthreads();

  if (tid < 64) {
    int q = tid;
    float mx = -1e30f;
    for (int k = 0; k < 64; ++k) mx = fmaxf(mx, Ps[q][k]);
    float sum = 0.f;
    for (int k = 0; k < 64; ++k) {
      float e = expf(Ps[q][k] - mx);
      Ps[q][k] = e;
      sum += e;
    }
    float inv = 1.0f / sum;
    for (int k = 0; k < 64; ++k) Ps[q][k] *= inv;
  }
  __syncthreads();

  float o[16];
#pragma unroll
  for (int i = 0; i < 16; ++i) o[i] = 0.f;
  for (int k = 0; k < 64; ++k) {
    float vv = Vs[k][lane];
#pragma unroll
    for (int i = 0; i < 16; ++i) o[i] += Ps[w + 4 * i][k] * vv;
  }
#pragma unroll
  for (int i = 0; i < 16; ++i) {
    int q = w + 4 * i;
    size_t off = (size_t)(bg * S + q) * H + hh * 64 + lane;
    ushort hi, lo;
    split2(o[i], hi, lo);
    outHi[off] = hi;
    outLo[off] = lo;
  }
}

__global__ __launch_bounds__(256) void embed_ln_kernel(const int* __restrict__ ids,
                                                       const float* __restrict__ we,
                                                       const float* __restrict__ pe,
                                                       const float* __restrict__ te,
                                                       const float* __restrict__ g,
                                                       const float* __restrict__ bta,
                                                       float* __restrict__ x,
                                                       ushort* __restrict__ xhi,
                                                       ushort* __restrict__ xlo) {
  __shared__ float buf[H];
  __shared__ float red[256];
  const int row = blockIdx.x;
  const int s = row % S;
  const int tid = threadIdx.x;
  const int id = ids[row];
  float local = 0.f;
  for (int i = tid; i < H; i += 256) {
    float v = we[(size_t)id * H + i] + pe[(size_t)s * H + i] + te[i];
    buf[i] = v;
    local += v;
  }
  red[tid] = local;
  __syncthreads();
  for (int st = 128; st > 0; st >>= 1) {
    if (tid < st) red[tid] += red[tid + st];
    __syncthreads();
  }
  float mean = red[0] * (1.0f / H);
  __syncthreads();
  float ls = 0.f;
  for (int i = tid; i < H; i += 256) {
    float d = buf[i] - mean;
    ls += d * d;
  }
  red[tid] = ls;
  __syncthreads();
  for (int st = 128; st > 0; st >>= 1) {
    if (tid < st) red[tid] += red[tid + st];
    __syncthreads();
  }
  float inv = 1.0f / sqrtf(red[0] * (1.0f / H) + 1e-12f);
  for (int i = tid; i < H; i += 256) {
    float o = (buf[i] - mean) * inv * g[i] + bta[i];
    size_t off = (size_t)row * H + i;
    x[off] = o;
    ushort hi, lo;
    split2(o, hi, lo);
    xhi[off] = hi;
    xlo[off] = lo;
  }
}

// x = LayerNorm(x + y) * g + b ; also emit hi/lo bf16 of the result
__global__ __launch_bounds__(256) void add_ln_kernel(float* __restrict__ x,
                                                     const float* __restrict__ y,
                                                     const float* __restrict__ g,
                                                     const float* __restrict__ bta,
                                                     ushort* __restrict__ xhi,
                                                     ushort* __restrict__ xlo) {
  __shared__ float buf[H];
  __shared__ float red[256];
  const size_t row = blockIdx.x;
  const int tid = threadIdx.x;
  float local = 0.f;
  for (int i = tid; i < H; i += 256) {
    float v = x[row * H + i] + y[row * H + i];
    buf[i] = v;
    local += v;
  }
  red[tid] = local;
  __syncthreads();
  for (int st = 128; st > 0; st >>= 1) {
    if (tid < st) red[tid] += red[tid + st];
    __syncthreads();
  }
  float mean = red[0] * (1.0f / H);
  __syncthreads();
  float ls = 0.f;
  for (int i = tid; i < H; i += 256) {
    float d = buf[i] - mean;
    ls += d * d;
  }
  red[tid] = ls;
  __syncthreads();
  for (int st = 128; st > 0; st >>= 1) {
    if (tid < st) red[tid] += red[tid + st];
    __syncthreads();
  }
  float inv = 1.0f / sqrtf(red[0] * (1.0f / H) + 1e-12f);
  for (int i = tid; i < H; i += 256) {
    float o = (buf[i] - mean) * inv * g[i] + bta[i];
    size_t off = row * H + i;
    x[off] = o;
    ushort hi, lo;
    split2(o, hi, lo);
    xhi[off] = hi;
    xlo[off] = lo;
  }
}

__global__ __launch_bounds__(256) void fc_kernel(const float* __restrict__ x,
                                                 const float* __restrict__ w,
                                                 const float* __restrict__ bias,
                                                 float* __restrict__ logits) {
  __shared__ float xs[H];
  const size_t row = blockIdx.x;
  const int tid = threadIdx.x;
  for (int i = tid; i < H; i += 256) xs[i] = x[row * H + i];
  __syncthreads();
  const int j = tid >> 4, l = tid & 15;
  if (j < T) {
    float s = 0.f;
    for (int k = l; k < H; k += 16) s += xs[k] * w[(size_t)k * T + j];
#pragma unroll
    for (int d = 8; d > 0; d >>= 1) s += __shfl_down(s, d, 16);
    if (l == 0) logits[row * T + j] = s + bias[j];
  }
}

__global__ __launch_bounds__(64) void crf_llh_kernel(const float* __restrict__ em,
                                                     const int* __restrict__ label,
                                                     const int* __restrict__ mask,
                                                     const float* __restrict__ start,
                                                     const float* __restrict__ endw,
                                                     const float* __restrict__ trans,
                                                     float* __restrict__ llh) {
  const int b = blockIdx.x;
  const int c = threadIdx.x;
  __shared__ float alpha[T];
  __shared__ float tr[T][T];
  for (int i = c; i < T * T; i += 64) tr[i / T][i % T] = trans[i];
  if (c < T) alpha[c] = start[c] + em[(size_t)b * S * T + c];
  __syncthreads();
  for (int s = 1; s < S; ++s) {
    float a = 0.f;
    if (c < T) {
      float mx = -1e30f;
      for (int p = 0; p < T; ++p) mx = fmaxf(mx, alpha[p] + tr[p][c]);
      float sum = 0.f;
      for (int p = 0; p < T; ++p) sum += expf(alpha[p] + tr[p][c] - mx);
      a = mx + logf(sum) + em[((size_t)b * S + s) * T + c];
    }
    __syncthreads();
    if (c < T) {
      float m = (float)mask[b * S + s];
      alpha[c] = (m > 0.f) ? a : alpha[c];
    }
    __syncthreads();
  }
  if (c == 0) {
    float mx = -1e30f;
    for (int p = 0; p < T; ++p) mx = fmaxf(mx, alpha[p] + endw[p]);
    float sum = 0.f;
    for (int p = 0; p < T; ++p) sum += expf(alpha[p] + endw[p] - mx);
    float denom = mx + logf(sum);

    int t0 = label[b * S];
    float score = start[t0] + em[(size_t)b * S * T + t0];
    int prev = t0;
    for (int s = 1; s < S; ++s) {
      int tc = label[b * S + s];
      float m = (float)mask[b * S + s];
      score += (tr[prev][tc] + em[((size_t)b * S + s) * T + tc]) * m;
      prev = tc;
    }
    int msum = 0;
    for (int s = 0; s < S; ++s) msum += mask[b * S + s];
    score += endw[label[b * S + (msum - 1)]];
    llh[b] = score - denom;
  }
}

__global__ __launch_bounds__(256) void loss_kernel(const float* __restrict__ llh,
                                                   float* __restrict__ out) {
  __shared__ float red[256];
  const int tid = threadIdx.x;
  red[tid] = llh[tid];  // B == 256
  __syncthreads();
  for (int st = 128; st > 0; st >>= 1) {
    if (tid < st) red[tid] += red[tid + st];
    __syncthreads();
  }
  if (tid == 0) out[BS] = -red[0] * (1.0f / B);
}

__global__ __launch_bounds__(64) void viterbi_kernel(const float* __restrict__ em,
                                                     const int* __restrict__ mask,
                                                     const float* __restrict__ start,
                                                     const float* __restrict__ endw,
                                                     const float* __restrict__ trans,
                                                     float* __restrict__ pred) {
  const int b = blockIdx.x;
  const int c = threadIdx.x;
  __shared__ float sc[T];
  __shared__ float tr[T][T];
  __shared__ int hist[S - 1][T];
  for (int i = c; i < T * T; i += 64) tr[i / T][i % T] = trans[i];
  if (c < T) sc[c] = start[c] + em[(size_t)b * S * T + c];
  __syncthreads();
  for (int s = 1; s < S; ++s) {
    float bestv = -1e30f;
    int bestp = 0;
    if (c < T) {
      for (int p = 0; p < T; ++p) {
        float v = sc[p] + tr[p][c];
        if (v > bestv) { bestv = v; bestp = p; }
      }
      hist[s - 1][c] = bestp;
    }
    __syncthreads();
    if (c < T) {
      float m = (float)mask[b * S + s];
      sc[c] = (m > 0.f) ? (bestv + em[((size_t)b * S + s) * T + c]) : sc[c];
    }
    __syncthreads();
  }
  if (c == 0) {
    float bv = -1e30f;
    int last = 0;
    for (int p = 0; p < T; ++p) {
      float v = sc[p] + endw[p];
      if (v > bv) { bv = v; last = p; }
    }
    pred[b * S + (S - 1)] = (float)last;
    int t = last;
    for (int hs = S - 2; hs >= 0; --hs) {
      if (mask[b * S + hs + 1] > 0) t = hist[hs][t];
      pred[b * S + hs] = (float)t;
    }
  }
}

}  // namespace

extern "C" void kernel_launch(void* const* d_in, const int* in_sizes, int n_in,
                              void* d_out, int out_size, void* d_ws, size_t ws_size,
                              hipStream_t stream) {
  (void)in_sizes; (void)n_in; (void)out_size; (void)ws_size;
  const int* input_ids = (const int*)d_in[0];
  const int* attn_mask = (const int*)d_in[1];
  const int* label = (const int*)d_in[2];
  const float* word_emb = (const float*)d_in[3];
  const float* pos_emb = (const float*)d_in[4];
  const float* tok_emb = (const float*)d_in[5];
  const float* eg = (const float*)d_in[6];
  const float* ebt = (const float*)d_in[7];
  const float* Wqkv = (const float*)d_in[8];
  const float* bqkv = (const float*)d_in[9];
  const float* Wo = (const float*)d_in[10];
  const float* bo = (const float*)d_in[11];
  const float* ln1g = (const float*)d_in[12];
  const float* ln1b = (const float*)d_in[13];
  const float* W1 = (const float*)d_in[14];
  const float* b1 = (const float*)d_in[15];
  const float* W2 = (const float*)d_in[16];
  const float* b2 = (const float*)d_in[17];
  const float* ln2g = (const float*)d_in[18];
  const float* ln2b = (const float*)d_in[19];
  const float* fc_w = (const float*)d_in[20];
  const float* fc_b = (const float*)d_in[21];
  const float* crf_start = (const float*)d_in[22];
  const float* crf_end = (const float*)d_in[23];
  const float* crf_trans = (const float*)d_in[24];
  float* out = (float*)d_out;

  // ---- workspace layout (bytes) ----
  char* p = (char*)d_ws;
  float* x = (float*)p;            p += (size_t)BS * H * 4;
  float* tmpA = (float*)p;         p += (size_t)BS * H * 4;
  ushort* xhi = (ushort*)p;        p += (size_t)BS * H * 2;
  ushort* xlo = (ushort*)p;        p += (size_t)BS * H * 2;
  ushort* whiQ = (ushort*)p;       p += (size_t)3 * H * H * 2;
  ushort* wloQ = (ushort*)p;       p += (size_t)3 * H * H * 2;
  ushort* whiO = (ushort*)p;       p += (size_t)H * H * 2;
  ushort* wloO = (ushort*)p;       p += (size_t)H * H * 2;
  ushort* whiF1 = (ushort*)p;      p += (size_t)H * F * 2;
  ushort* wloF1 = (ushort*)p;      p += (size_t)H * F * 2;
  ushort* whiF2 = (ushort*)p;      p += (size_t)F * H * 2;
  ushort* wloF2 = (ushort*)p;      p += (size_t)F * H * 2;
  char* big = p;                   p += (size_t)RF * F * 2 * 2;  // union region (100.7 MB)
  float* logits = (float*)p;       p += (size_t)BS * T * 4;
  float* llh = (float*)p;          p += (size_t)B * 4;
  // qkv phase views of `big`:
  float* qkvC = (float*)big;                                   // [RC, 3H] fp32
  ushort* attnHi = (ushort*)(big + (size_t)RC * 3 * H * 4);    // [BS, H]
  ushort* attnLo = attnHi + (size_t)BS * H;
  // ffn phase views of `big`:
  ushort* hHi = (ushort*)big;                                  // [RF, F]
  ushort* hLo = hHi + (size_t)RF * F;

  embed_ln_kernel<<<BS, 256, 0, stream>>>(input_ids, word_emb, pos_emb, tok_emb, eg, ebt,
                                          x, xhi, xlo);

  for (int l = 0; l < L; ++l) {
    const float* wqkv_l = Wqkv + (size_t)l * H * 3 * H;
    const float* bqkv_l = bqkv + (size_t)l * 3 * H;
    const float* wo_l = Wo + (size_t)l * H * H;
    const float* bo_l = bo + (size_t)l * H;
    const float* g1 = ln1g + (size_t)l * H;
    const float* be1 = ln1b + (size_t)l * H;
    const float* w1_l = W1 + (size_t)l * H * F;
    const float* b1_l = b1 + (size_t)l * F;
    const float* w2_l = W2 + (size_t)l * F * H;
    const float* b2_l = b2 + (size_t)l * H;
    const float* g2 = ln2g + (size_t)l * H;
    const float* be2 = ln2b + (size_t)l * H;

    // per-layer weight transpose + bf16 hi/lo split
    convert_w_t<<<dim3(3 * H / 32, H / 32), 256, 0, stream>>>(wqkv_l, whiQ, wloQ, H, 3 * H);
    convert_w_t<<<dim3(H / 32, H / 32), 256, 0, stream>>>(wo_l, whiO, wloO, H, H);
    convert_w_t<<<dim3(F / 32, H / 32), 256, 0, stream>>>(w1_l, whiF1, wloF1, H, F);
    convert_w_t<<<dim3(H / 32, F / 32), 256, 0, stream>>>(w2_l, whiF2, wloF2, F, H);

    for (int ch = 0; ch < NC; ++ch) {
      gemm_mfma<0><<<dim3(3 * H / 128, RC / 128), 256, 0, stream>>>(
          xhi + (size_t)ch * RC * H, xlo + (size_t)ch * RC * H, whiQ, wloQ, bqkv_l,
          qkvC, nullptr, nullptr, RC, 3 * H, H);
      attn_kernel<<<(RC / S) * NH, 256, 0, stream>>>(qkvC, attn_mask, attnHi, attnLo,
                                                     ch * (RC / S));
    }
    gemm_mfma<0><<<dim3(H / 128, BS / 128), 256, 0, stream>>>(
        attnHi, attnLo, whiO, wloO, bo_l, tmpA, nullptr, nullptr, BS, H, H);
    add_ln_kernel<<<BS, 256, 0, stream>>>(x, tmpA, g1, be1, xhi, xlo);

    for (int c2 = 0; c2 < NF; ++c2) {
      gemm_mfma<1><<<dim3(F / 128, RF / 128), 256, 0, stream>>>(
          xhi + (size_t)c2 * RF * H, xlo + (size_t)c2 * RF * H, whiF1, wloF1, b1_l,
          nullptr, hHi, hLo, RF, F, H);
      gemm_mfma<0><<<dim3(H / 128, RF / 128), 256, 0, stream>>>(
          hHi, hLo, whiF2, wloF2, b2_l, tmpA + (size_t)c2 * RF * H, nullptr, nullptr,
          RF, H, F);
    }
    add_ln_kernel<<<BS, 256, 0, stream>>>(x, tmpA, g2, be2, xhi, xlo);
  }

  fc_kernel<<<BS, 256, 0, stream>>>(x, fc_w, fc_b, logits);
  crf_llh_kernel<<<B, 64, 0, stream>>>(logits, label, attn_mask, crf_start, crf_end, crf_trans, llh);
  loss_kernel<<<1, 256, 0, stream>>>(llh, out);
  viterbi_kernel<<<B, 64, 0, stream>>>(logits, attn_mask, crf_start, crf_end, crf_trans, out);
}

// Round 3
// 13717.308 us; speedup vs baseline: 3.3218x; 1.0903x over previous
//
#include <hip/hip_runtime.h>
#include <hip/hip_bf16.h>
#include <math.h>

namespace {

constexpr int B = 256, S = 64, H = 768, L = 12, NH = 12, F = 3072, T = 11;
constexpr int BS = B * S;   // 16384 rows
constexpr int RC = 8192;    // rows per chunk
constexpr int NCH = BS / RC;

typedef __attribute__((ext_vector_type(8))) short short8;
typedef __attribute__((ext_vector_type(4))) float f32x4;

__device__ __forceinline__ float gelu_tanh(float v) {
  float u = 0.7978845608028654f * (v + 0.044715f * v * v * v);
  u = fminf(fmaxf(u, -10.f), 10.f);
  float t = __expf(2.f * u);
  return 0.5f * v * (1.0f + (t - 1.f) / (t + 1.f));
}

// RNE float->bf16
__device__ __forceinline__ ushort f2bf(float v) {
  union { float f; unsigned u; } c; c.f = v;
  unsigned r = (c.u + 0x7fffu + ((c.u >> 16) & 1u)) >> 16;
  return (ushort)r;
}
__device__ __forceinline__ float bf2f(ushort u) {
  union { unsigned u; float f; } c; c.u = ((unsigned)u) << 16;
  return c.f;
}
// pack value as (hi bf16 in low16) | (lo bf16 in high16)
__device__ __forceinline__ uint packhl(float v) {
  ushort hi = f2bf(v);
  ushort lo = f2bf(v - bf2f(hi));
  return (uint)hi | ((uint)lo << 16);
}
// reconstruct fp32 from packed hi/lo
__device__ __forceinline__ float unpackhl(uint u) {
  union { unsigned u; float f; } a, b;
  a.u = u << 16;            // hi bf16 -> f32
  b.u = u & 0xffff0000u;    // lo bf16 -> f32
  return a.f + b.f;
}

__device__ __forceinline__ uint prm(uint a, uint b, uint s) {
#if __has_builtin(__builtin_amdgcn_perm)
  return __builtin_amdgcn_perm(a, b, s);
#else
  uint r = 0;
  for (int i = 0; i < 4; ++i) {
    uint sel = (s >> (8 * i)) & 0xff;
    uint byte = sel < 4 ? (b >> (8 * sel)) & 0xff : (a >> (8 * (sel - 4))) & 0xff;
    r |= byte << (8 * i);
  }
  return r;
#endif
}

union S8U { uint u[4]; short8 s; };

// v0 = packed elems k..k+3, v1 = k+4..k+7 -> hi-frag / lo-frag short8
__device__ __forceinline__ void unpack_frag(uint4 v0, uint4 v1, short8& hi, short8& lo) {
  S8U h, l;
  h.u[0] = prm(v0.y, v0.x, 0x05040100u);
  l.u[0] = prm(v0.y, v0.x, 0x07060302u);
  h.u[1] = prm(v0.w, v0.z, 0x05040100u);
  l.u[1] = prm(v0.w, v0.z, 0x07060302u);
  h.u[2] = prm(v1.y, v1.x, 0x05040100u);
  l.u[2] = prm(v1.y, v1.x, 0x07060302u);
  h.u[3] = prm(v1.w, v1.z, 0x05040100u);
  l.u[3] = prm(v1.w, v1.z, 0x07060302u);
  hi = h.s;
  lo = l.s;
}

#define GLOAD_LDS16(gptr, ldsptr)                                                        \
  __builtin_amdgcn_global_load_lds((const __attribute__((address_space(1))) void*)(gptr), \
                                   (__attribute__((address_space(3))) void*)(ldsptr), 16, 0, 0)

// C = (Ahi+Alo)[M,K] @ (Bhi+Blo)[N,K]^T via 3 bf16 MFMA products, fp32 accum.
// A/B packed u32 (hi|lo<<16) per element. Strides in elements.
// MODE 1: gelu(v+bias) -> packed u32 out. MODE 2: v+bias -> packed u32 out.
// MODE 3: atomicAdd fp32 (no bias; dst prefilled with bias).
template <int MODE>
__global__ __launch_bounds__(256) void gemm_mfma(const uint* __restrict__ A,
                                                 const uint* __restrict__ Bw,
                                                 const float* __restrict__ bias,
                                                 float* __restrict__ outF,
                                                 uint* __restrict__ outU,
                                                 int lda, int ldb, int ldc, int Ksz) {
  __shared__ uint sm[2][2][128 * 32];  // [buf][A/B][row][32 kelems], 128B rows
  const int tid = threadIdx.x;
  const int w = tid >> 6;
  const int lane = tid & 63;

  // bijective XCD-aware swizzle (all grids have gx*gy % 8 == 0)
  const int gx = gridDim.x;
  const int flat = blockIdx.y * gx + blockIdx.x;
  const int q = (gx * (int)gridDim.y) >> 3;
  const int swz = (flat & 7) * q + (flat >> 3);
  const int bm = (swz / gx) * 128;
  const int bn = (swz % gx) * 128;
  const int kStart = blockIdx.z * Ksz;

  // staging constants: lane l -> row +l/8, 16B-block l%8; source k-block XOR-swizzled
  const int srow = lane >> 3;
  const int sswz = (((lane & 7) ^ srow) << 2);  // element offset in 32-elem window
  const uint* Ab = A + (size_t)(bm + w * 32 + srow) * lda + kStart + sswz;
  const uint* Bb = Bw + (size_t)(bn + w * 32 + srow) * ldb + kStart + sswz;

#define STAGE(buf, kt)                                                             \
  do {                                                                             \
    _Pragma("unroll") for (int i_ = 0; i_ < 4; ++i_) {                             \
      GLOAD_LDS16(Ab + (kt) + (size_t)(i_ * 8) * lda,                              \
                  &sm[buf][0][(w * 32 + i_ * 8) * 32]);                            \
      GLOAD_LDS16(Bb + (kt) + (size_t)(i_ * 8) * ldb,                              \
                  &sm[buf][1][(w * 32 + i_ * 8) * 32]);                            \
    }                                                                              \
  } while (0)

  // fragment read constants (16x16x32: A-row = lane&15, k = 8*(lane>>4)+0..7)
  const int wm = w >> 1, wn = w & 1;
  const int fr = lane & 15;
  const int fs = fr & 7;                 // row-based XOR key
  const int kq = (lane >> 4) << 1;       // logical 16B-block of k-span start
  const int kb0 = kq ^ fs;               // swizzled block addresses
  const int kb1 = kb0 ^ 1;

  f32x4 acc[4][4] = {};
  const int NT = Ksz / 32;

  STAGE(0, 0);
  __syncthreads();

  for (int t = 0; t < NT; ++t) {
    const int cur = t & 1;
    short8 ah[4], al[4], bh[4], bl[4];
#pragma unroll
    for (int i = 0; i < 4; ++i) {
      const uint* base = &sm[cur][0][(wm * 64 + i * 16 + fr) * 32];
      uint4 v0 = *(const uint4*)(base + kb0 * 4);
      uint4 v1 = *(const uint4*)(base + kb1 * 4);
      unpack_frag(v0, v1, ah[i], al[i]);
    }
#pragma unroll
    for (int i = 0; i < 4; ++i) {
      const uint* base = &sm[cur][1][(wn * 64 + i * 16 + fr) * 32];
      uint4 v0 = *(const uint4*)(base + kb0 * 4);
      uint4 v1 = *(const uint4*)(base + kb1 * 4);
      unpack_frag(v0, v1, bh[i], bl[i]);
    }
    if (t + 1 < NT) STAGE(cur ^ 1, (t + 1) * 32);
#pragma unroll
    for (int mi = 0; mi < 4; ++mi)
#pragma unroll
      for (int ni = 0; ni < 4; ++ni) {
        acc[mi][ni] = __builtin_amdgcn_mfma_f32_16x16x32_bf16(ah[mi], bh[ni], acc[mi][ni], 0, 0, 0);
        acc[mi][ni] = __builtin_amdgcn_mfma_f32_16x16x32_bf16(ah[mi], bl[ni], acc[mi][ni], 0, 0, 0);
        acc[mi][ni] = __builtin_amdgcn_mfma_f32_16x16x32_bf16(al[mi], bh[ni], acc[mi][ni], 0, 0, 0);
      }
    __syncthreads();  // drains vmcnt(0): next buffer staged & this buffer's reads done
  }
#undef STAGE

  const int erow = (lane >> 4) << 2;  // C/D: col=lane&15, row=(lane>>4)*4+e
#pragma unroll
  for (int ni = 0; ni < 4; ++ni) {
    const int col = bn + wn * 64 + ni * 16 + fr;
    const float bv = (MODE == 3) ? 0.f : bias[col];
#pragma unroll
    for (int mi = 0; mi < 4; ++mi) {
#pragma unroll
      for (int e = 0; e < 4; ++e) {
        const int row = bm + wm * 64 + mi * 16 + erow + e;
        float v = acc[mi][ni][e] + bv;
        if (MODE == 1) {
          outU[(size_t)row * ldc + col] = packhl(gelu_tanh(v));
        } else if (MODE == 2) {
          outU[(size_t)row * ldc + col] = packhl(v);
        } else {
          atomicAdd(&outF[(size_t)row * ldc + col], v);
        }
      }
    }
  }
}

// W[K][N] fp32 -> packed-hi/lo u32, transposed to [N][K]
__global__ __launch_bounds__(256) void convert_w_t(const float* __restrict__ W,
                                                   uint* __restrict__ WT, int K, int N) {
  __shared__ float tile[32][33];
  const int kb = blockIdx.y * 32, nb = blockIdx.x * 32;
  const int tr = threadIdx.x >> 5;
  const int tc = threadIdx.x & 31;
#pragma unroll
  for (int p = 0; p < 4; ++p) {
    int r = tr + p * 8;
    tile[r][tc] = W[(size_t)(kb + r) * N + nb + tc];
  }
  __syncthreads();
#pragma unroll
  for (int p = 0; p < 4; ++p) {
    int n = tr + p * 8;
    WT[(size_t)(nb + n) * K + kb + tc] = packhl(tile[tc][n]);
  }
}

__global__ __launch_bounds__(256) void fill_bias_kernel(float* __restrict__ dst,
                                                        const float* __restrict__ bias) {
  const size_t i4 = (size_t)blockIdx.x * 256 + threadIdx.x;  // BS*H/4 total
  const int c4 = (int)(i4 % (H / 4));
  ((float4*)dst)[i4] = ((const float4*)bias)[c4];
}

// One block per (local batch, head). qkv packed u32 [row][3H]; writes output
// IN PLACE into the Q-slot columns (block reads all its Q/K/V to LDS first).
__global__ __launch_bounds__(256) void attn_kernel(uint* __restrict__ qkv,
                                                   const int* __restrict__ mask, int b0) {
  __shared__ float smem[64 * 64 + 64 * 66 + 64 * 64];  // Qs | KsT | Vs ; Ps aliases
  float (*Qs)[64] = (float (*)[64])smem;
  float (*KsT)[66] = (float (*)[66])(smem + 64 * 64);
  float (*Vs)[64] = (float (*)[64])(smem + 64 * 64 + 64 * 66);
  float (*Ps)[65] = (float (*)[65])smem;

  const int bl = blockIdx.x / NH;
  const int hh = blockIdx.x % NH;
  const int bg = b0 + bl;
  const int tid = threadIdx.x;
  const int lane = tid & 63;
  const int w = tid >> 6;

  for (int i = 0; i < 16; ++i) {
    int idx = tid + i * 256;
    int r = idx >> 6, d = idx & 63;
    size_t base = (size_t)(bl * 64 + r) * (3 * H) + hh * 64 + d;
    Qs[r][d] = unpackhl(qkv[base]);
    KsT[d][r] = unpackhl(qkv[base + H]);
    Vs[r][d] = unpackhl(qkv[base + 2 * H]);
  }
  __syncthreads();

  float sc[16];
#pragma unroll
  for (int i = 0; i < 16; ++i) sc[i] = 0.f;
  for (int d = 0; d < 64; ++d) {
    float kv = KsT[d][lane];
#pragma unroll
    for (int i = 0; i < 16; ++i) sc[i] += Qs[w + 4 * i][d] * kv;
  }
  __syncthreads();
  float biask = (1.0f - (float)mask[bg * S + lane]) * -1e9f;
#pragma unroll
  for (int i = 0; i < 16; ++i) Ps[w + 4 * i][lane] = sc[i] * 0.125f + biask;
  __syncthreads();

  if (tid < 64) {
    int qr = tid;
    float mx = -1e30f;
    for (int k = 0; k < 64; ++k) mx = fmaxf(mx, Ps[qr][k]);
    float sum = 0.f;
    for (int k = 0; k < 64; ++k) {
      float e = expf(Ps[qr][k] - mx);
      Ps[qr][k] = e;
      sum += e;
    }
    float inv = 1.0f / sum;
    for (int k = 0; k < 64; ++k) Ps[qr][k] *= inv;
  }
  __syncthreads();

  float o[16];
#pragma unroll
  for (int i = 0; i < 16; ++i) o[i] = 0.f;
  for (int k = 0; k < 64; ++k) {
    float vv = Vs[k][lane];
#pragma unroll
    for (int i = 0; i < 16; ++i) o[i] += Ps[w + 4 * i][k] * vv;
  }
#pragma unroll
  for (int i = 0; i < 16; ++i) {
    int qr = w + 4 * i;
    qkv[(size_t)(bl * 64 + qr) * (3 * H) + hh * 64 + lane] = packhl(o[i]);
  }
}

__global__ __launch_bounds__(256) void embed_ln_kernel(const int* __restrict__ ids,
                                                       const float* __restrict__ we,
                                                       const float* __restrict__ pe,
                                                       const float* __restrict__ te,
                                                       const float* __restrict__ g,
                                                       const float* __restrict__ bta,
                                                       float* __restrict__ x,
                                                       uint* __restrict__ xhl) {
  __shared__ float buf[H];
  __shared__ float red[256];
  const int row = blockIdx.x;
  const int s = row % S;
  const int tid = threadIdx.x;
  const int id = ids[row];
  float local = 0.f;
  for (int i = tid; i < H; i += 256) {
    float v = we[(size_t)id * H + i] + pe[(size_t)s * H + i] + te[i];
    buf[i] = v;
    local += v;
  }
  red[tid] = local;
  __syncthreads();
  for (int st = 128; st > 0; st >>= 1) {
    if (tid < st) red[tid] += red[tid + st];
    __syncthreads();
  }
  float mean = red[0] * (1.0f / H);
  __syncthreads();
  float ls = 0.f;
  for (int i = tid; i < H; i += 256) {
    float d = buf[i] - mean;
    ls += d * d;
  }
  red[tid] = ls;
  __syncthreads();
  for (int st = 128; st > 0; st >>= 1) {
    if (tid < st) red[tid] += red[tid + st];
    __syncthreads();
  }
  float inv = 1.0f / sqrtf(red[0] * (1.0f / H) + 1e-12f);
  for (int i = tid; i < H; i += 256) {
    float o = (buf[i] - mean) * inv * g[i] + bta[i];
    size_t off = (size_t)row * H + i;
    x[off] = o;
    xhl[off] = packhl(o);
  }
}

// x = LayerNorm(x + y) * g + b ; also emit packed hi/lo
__global__ __launch_bounds__(256) void add_ln_kernel(float* __restrict__ x,
                                                     const float* __restrict__ y,
                                                     const float* __restrict__ g,
                                                     const float* __restrict__ bta,
                                                     uint* __restrict__ xhl) {
  __shared__ float buf[H];
  __shared__ float red[256];
  const size_t row = blockIdx.x;
  const int tid = threadIdx.x;
  float local = 0.f;
  for (int i = tid; i < H; i += 256) {
    float v = x[row * H + i] + y[row * H + i];
    buf[i] = v;
    local += v;
  }
  red[tid] = local;
  __syncthreads();
  for (int st = 128; st > 0; st >>= 1) {
    if (tid < st) red[tid] += red[tid + st];
    __syncthreads();
  }
  float mean = red[0] * (1.0f / H);
  __syncthreads();
  float ls = 0.f;
  for (int i = tid; i < H; i += 256) {
    float d = buf[i] - mean;
    ls += d * d;
  }
  red[tid] = ls;
  __syncthreads();
  for (int st = 128; st > 0; st >>= 1) {
    if (tid < st) red[tid] += red[tid + st];
    __syncthreads();
  }
  float inv = 1.0f / sqrtf(red[0] * (1.0f / H) + 1e-12f);
  for (int i = tid; i < H; i += 256) {
    float o = (buf[i] - mean) * inv * g[i] + bta[i];
    size_t off = row * H + i;
    x[off] = o;
    xhl[off] = packhl(o);
  }
}

__global__ __launch_bounds__(256) void fc_kernel(const float* __restrict__ x,
                                                 const float* __restrict__ w,
                                                 const float* __restrict__ bias,
                                                 float* __restrict__ logits) {
  __shared__ float xs[H];
  const size_t row = blockIdx.x;
  const int tid = threadIdx.x;
  for (int i = tid; i < H; i += 256) xs[i] = x[row * H + i];
  __syncthreads();
  const int j = tid >> 4, l = tid & 15;
  if (j < T) {
    float s = 0.f;
    for (int k = l; k < H; k += 16) s += xs[k] * w[(size_t)k * T + j];
#pragma unroll
    for (int d = 8; d > 0; d >>= 1) s += __shfl_down(s, d, 16);
    if (l == 0) logits[row * T + j] = s + bias[j];
  }
}

__global__ __launch_bounds__(64) void crf_llh_kernel(const float* __restrict__ em,
                                                     const int* __restrict__ label,
                                                     const int* __restrict__ mask,
                                                     const float* __restrict__ start,
                                                     const float* __restrict__ endw,
                                                     const float* __restrict__ trans,
                                                     float* __restrict__ llh) {
  const int b = blockIdx.x;
  const int c = threadIdx.x;
  __shared__ float alpha[T];
  __shared__ float tr[T][T];
  for (int i = c; i < T * T; i += 64) tr[i / T][i % T] = trans[i];
  if (c < T) alpha[c] = start[c] + em[(size_t)b * S * T + c];
  __syncthreads();
  for (int s = 1; s < S; ++s) {
    float a = 0.f;
    if (c < T) {
      float mx = -1e30f;
      for (int p = 0; p < T; ++p) mx = fmaxf(mx, alpha[p] + tr[p][c]);
      float sum = 0.f;
      for (int p = 0; p < T; ++p) sum += expf(alpha[p] + tr[p][c] - mx);
      a = mx + logf(sum) + em[((size_t)b * S + s) * T + c];
    }
    __syncthreads();
    if (c < T) {
      float m = (float)mask[b * S + s];
      alpha[c] = (m > 0.f) ? a : alpha[c];
    }
    __syncthreads();
  }
  if (c == 0) {
    float mx = -1e30f;
    for (int p = 0; p < T; ++p) mx = fmaxf(mx, alpha[p] + endw[p]);
    float sum = 0.f;
    for (int p = 0; p < T; ++p) sum += expf(alpha[p] + endw[p] - mx);
    float denom = mx + logf(sum);

    int t0 = label[b * S];
    float score = start[t0] + em[(size_t)b * S * T + t0];
    int prev = t0;
    for (int s = 1; s < S; ++s) {
      int tc = label[b * S + s];
      float m = (float)mask[b * S + s];
      score += (tr[prev][tc] + em[((size_t)b * S + s) * T + tc]) * m;
      prev = tc;
    }
    int msum = 0;
    for (int s = 0; s < S; ++s) msum += mask[b * S + s];
    score += endw[label[b * S + (msum - 1)]];
    llh[b] = score - denom;
  }
}

__global__ __launch_bounds__(256) void loss_kernel(const float* __restrict__ llh,
                                                   float* __restrict__ out) {
  __shared__ float red[256];
  const int tid = threadIdx.x;
  red[tid] = llh[tid];  // B == 256
  __syncthreads();
  for (int st = 128; st > 0; st >>= 1) {
    if (tid < st) red[tid] += red[tid + st];
    __syncthreads();
  }
  if (tid == 0) out[BS] = -red[0] * (1.0f / B);
}

__global__ __launch_bounds__(64) void viterbi_kernel(const float* __restrict__ em,
                                                     const int* __restrict__ mask,
                                                     const float* __restrict__ start,
                                                     const float* __restrict__ endw,
                                                     const float* __restrict__ trans,
                                                     float* __restrict__ pred) {
  const int b = blockIdx.x;
  const int c = threadIdx.x;
  __shared__ float sc[T];
  __shared__ float tr[T][T];
  __shared__ int hist[S - 1][T];
  for (int i = c; i < T * T; i += 64) tr[i / T][i % T] = trans[i];
  if (c < T) sc[c] = start[c] + em[(size_t)b * S * T + c];
  __syncthreads();
  for (int s = 1; s < S; ++s) {
    float bestv = -1e30f;
    int bestp = 0;
    if (c < T) {
      for (int p = 0; p < T; ++p) {
        float v = sc[p] + tr[p][c];
        if (v > bestv) { bestv = v; bestp = p; }
      }
      hist[s - 1][c] = bestp;
    }
    __syncthreads();
    if (c < T) {
      float m = (float)mask[b * S + s];
      sc[c] = (m > 0.f) ? (bestv + em[((size_t)b * S + s) * T + c]) : sc[c];
    }
    __syncthreads();
  }
  if (c == 0) {
    float bv = -1e30f;
    int last = 0;
    for (int p = 0; p < T; ++p) {
      float v = sc[p] + endw[p];
      if (v > bv) { bv = v; last = p; }
    }
    pred[b * S + (S - 1)] = (float)last;
    int t = last;
    for (int hs = S - 2; hs >= 0; --hs) {
      if (mask[b * S + hs + 1] > 0) t = hist[hs][t];
      pred[b * S + hs] = (float)t;
    }
  }
}

}  // namespace

extern "C" void kernel_launch(void* const* d_in, const int* in_sizes, int n_in,
                              void* d_out, int out_size, void* d_ws, size_t ws_size,
                              hipStream_t stream) {
  (void)in_sizes; (void)n_in; (void)out_size; (void)ws_size;
  const int* input_ids = (const int*)d_in[0];
  const int* attn_mask = (const int*)d_in[1];
  const int* label = (const int*)d_in[2];
  const float* word_emb = (const float*)d_in[3];
  const float* pos_emb = (const float*)d_in[4];
  const float* tok_emb = (const float*)d_in[5];
  const float* eg = (const float*)d_in[6];
  const float* ebt = (const float*)d_in[7];
  const float* Wqkv = (const float*)d_in[8];
  const float* bqkv = (const float*)d_in[9];
  const float* Wo = (const float*)d_in[10];
  const float* bo = (const float*)d_in[11];
  const float* ln1g = (const float*)d_in[12];
  const float* ln1b = (const float*)d_in[13];
  const float* W1 = (const float*)d_in[14];
  const float* b1 = (const float*)d_in[15];
  const float* W2 = (const float*)d_in[16];
  const float* b2 = (const float*)d_in[17];
  const float* ln2g = (const float*)d_in[18];
  const float* ln2b = (const float*)d_in[19];
  const float* fc_w = (const float*)d_in[20];
  const float* fc_b = (const float*)d_in[21];
  const float* crf_start = (const float*)d_in[22];
  const float* crf_end = (const float*)d_in[23];
  const float* crf_trans = (const float*)d_in[24];
  float* out = (float*)d_out;

  // ---- workspace layout (~281 MB, matches the proven round-2 footprint) ----
  char* p = (char*)d_ws;
  float* x = (float*)p;        p += (size_t)BS * H * 4;          // 50.3 MB
  float* tmpA = (float*)p;     p += (size_t)BS * H * 4;          // 50.3 MB
  uint* xhl = (uint*)p;        p += (size_t)BS * H * 4;          // 50.3 MB
  uint* wQ = (uint*)p;         p += (size_t)3 * H * H * 4;       // 7.1 MB  [3H][H]
  uint* wO = (uint*)p;         p += (size_t)H * H * 4;           // 2.4 MB  [H][H]
  uint* wF1 = (uint*)p;        p += (size_t)F * H * 4;           // 9.4 MB  [F][H]
  uint* wF2 = (uint*)p;        p += (size_t)H * F * 4;           // 9.4 MB  [H][F]
  uint* big = (uint*)p;        p += (size_t)RC * F * 4;          // 100.7 MB
  float* logits = (float*)p;   p += (size_t)BS * T * 4;
  float* llh = (float*)p;      p += (size_t)B * 4;
  uint* qkvU = big;   // [RC][3H] packed; attn out lands in Q-slot cols
  uint* hU = big;     // [RC][F] packed (FFN phase)

  embed_ln_kernel<<<BS, 256, 0, stream>>>(input_ids, word_emb, pos_emb, tok_emb, eg, ebt,
                                          x, xhl);

  for (int l = 0; l < L; ++l) {
    const float* wqkv_l = Wqkv + (size_t)l * H * 3 * H;
    const float* bqkv_l = bqkv + (size_t)l * 3 * H;
    const float* wo_l = Wo + (size_t)l * H * H;
    const float* bo_l = bo + (size_t)l * H;
    const float* g1 = ln1g + (size_t)l * H;
    const float* be1 = ln1b + (size_t)l * H;
    const float* w1_l = W1 + (size_t)l * H * F;
    const float* b1_l = b1 + (size_t)l * F;
    const float* w2_l = W2 + (size_t)l * F * H;
    const float* b2_l = b2 + (size_t)l * H;
    const float* g2 = ln2g + (size_t)l * H;
    const float* be2 = ln2b + (size_t)l * H;

    convert_w_t<<<dim3(3 * H / 32, H / 32), 256, 0, stream>>>(wqkv_l, wQ, H, 3 * H);
    convert_w_t<<<dim3(H / 32, H / 32), 256, 0, stream>>>(wo_l, wO, H, H);
    convert_w_t<<<dim3(F / 32, H / 32), 256, 0, stream>>>(w1_l, wF1, H, F);
    convert_w_t<<<dim3(H / 32, F / 32), 256, 0, stream>>>(w2_l, wF2, F, H);

    // ---- attention block ----
    fill_bias_kernel<<<BS * H / 4 / 256, 256, 0, stream>>>(tmpA, bo_l);
    for (int ch = 0; ch < NCH; ++ch) {
      gemm_mfma<2><<<dim3(3 * H / 128, RC / 128, 1), 256, 0, stream>>>(
          xhl + (size_t)ch * RC * H, wQ, bqkv_l, nullptr, qkvU, H, H, 3 * H, H);
      attn_kernel<<<(RC / S) * NH, 256, 0, stream>>>(qkvU, attn_mask, ch * (RC / S));
      gemm_mfma<3><<<dim3(H / 128, RC / 128, 2), 256, 0, stream>>>(
          qkvU, wO, nullptr, tmpA + (size_t)ch * RC * H, nullptr, 3 * H, H, H, H / 2);
    }
    add_ln_kernel<<<BS, 256, 0, stream>>>(x, tmpA, g1, be1, xhl);

    // ---- FFN block ----
    fill_bias_kernel<<<BS * H / 4 / 256, 256, 0, stream>>>(tmpA, b2_l);
    for (int ch = 0; ch < NCH; ++ch) {
      gemm_mfma<1><<<dim3(F / 128, RC / 128, 1), 256, 0, stream>>>(
          xhl + (size_t)ch * RC * H, wF1, b1_l, nullptr, hU, H, H, F, H);
      gemm_mfma<3><<<dim3(H / 128, RC / 128, 2), 256, 0, stream>>>(
          hU, wF2, nullptr, tmpA + (size_t)ch * RC * H, nullptr, F, F, H, F / 2);
    }
    add_ln_kernel<<<BS, 256, 0, stream>>>(x, tmpA, g2, be2, xhl);
  }

  fc_kernel<<<BS, 256, 0, stream>>>(x, fc_w, fc_b, logits);
  crf_llh_kernel<<<B, 64, 0, stream>>>(logits, label, attn_mask, crf_start, crf_end, crf_trans, llh);
  loss_kernel<<<1, 256, 0, stream>>>(llh, out);
  viterbi_kernel<<<B, 64, 0, stream>>>(logits, attn_mask, crf_start, crf_end, crf_trans, out);
}